// Round 1
// baseline (225.878 us; speedup 1.0000x reference)
//
#include <hip/hip_runtime.h>
#include <math.h>

#define HOUT 48
#define WOUT 320
#define NB   8
#define NBOX 64
#define NC   3
#define IMH  1024
#define IMW  1024

#define PIX_PER_CROP (HOUT * WOUT)          // 15360
#define BLK 256
#define BLKS_PER_CROP (PIX_PER_CROP / BLK)  // 60

__global__ __launch_bounds__(BLK) void rot_crop_kernel(
    const float* __restrict__ x,      // [NB, NC, IMH, IMW]
    const float* __restrict__ boxes,  // [NB, NBOX, 5]
    float* __restrict__ out)          // [NB*NBOX, NC, HOUT, WOUT]
{
    const int bn  = blockIdx.x / BLKS_PER_CROP;          // box index in [0, NB*NBOX)
    const int pix = (blockIdx.x % BLKS_PER_CROP) * BLK + threadIdx.x;
    const int j = pix % WOUT;   // output col
    const int i = pix / WOUT;   // output row
    const int b = bn / NBOX;    // batch image

    // Box params — block-uniform (bn depends only on blockIdx) -> scalar loads.
    const float* box = boxes + bn * 5;
    const float cx  = box[0];
    const float cy  = box[1];
    const float bw  = box[2];
    const float bh  = box[3];
    const float ang = box[4];

    // cv2 rect corner math (matches reference exactly)
    const float theta = ang * (-3.14159265358979323846f / 180.0f);
    float st, ct;
    __sincosf(theta, &st, &ct);
    const float bb = ct * 0.5f;
    const float aa = st * 0.5f;

    const float p0x = cx - aa * bh - bb * bw;
    const float p0y = cy + bb * bh - aa * bw;
    const float p1x = cx + aa * bh - bb * bw;
    const float p1y = cy - bb * bh - aa * bw;
    const float p2x = 2.0f * cx - p0x;
    const float p2y = 2.0f * cy - p0y;

    const float u = (float)j * (1.0f / (float)WOUT);
    const float v = (float)i * (1.0f / (float)HOUT);

    const float sx = p1x + u * (p2x - p1x) + v * (p0x - p1x);
    const float sy = p1y + u * (p2y - p1y) + v * (p0y - p1y);

    const float x0f = floorf(sx);
    const float y0f = floorf(sy);
    const float dx = sx - x0f;
    const float dy = sy - y0f;
    const int x0i = (int)x0f;
    const int y0i = (int)y0f;
    const int x1i = x0i + 1;
    const int y1i = y0i + 1;

    const bool vx0 = (x0i >= 0) & (x0i < IMW);
    const bool vx1 = (x1i >= 0) & (x1i < IMW);
    const bool vy0 = (y0i >= 0) & (y0i < IMH);
    const bool vy1 = (y1i >= 0) & (y1i < IMH);

    const int xc0 = min(max(x0i, 0), IMW - 1);
    const int xc1 = min(max(x1i, 0), IMW - 1);
    const int yc0 = min(max(y0i, 0), IMH - 1);
    const int yc1 = min(max(y1i, 0), IMH - 1);

    const float w00 = (1.0f - dx) * (1.0f - dy) * (float)(vx0 && vy0);
    const float w10 = dx * (1.0f - dy)          * (float)(vx1 && vy0);
    const float w01 = (1.0f - dx) * dy          * (float)(vx0 && vy1);
    const float w11 = dx * dy                   * (float)(vx1 && vy1);

    const long long o00 = (long long)yc0 * IMW + xc0;
    const long long o10 = (long long)yc0 * IMW + xc1;
    const long long o01 = (long long)yc1 * IMW + xc0;
    const long long o11 = (long long)yc1 * IMW + xc1;

    const float* img = x + (long long)b * NC * IMH * IMW;
    float* op = out + (long long)bn * NC * PIX_PER_CROP + pix;

#pragma unroll
    for (int c = 0; c < NC; ++c) {
        const float* ch = img + (long long)c * (IMH * IMW);
        const float acc = ch[o00] * w00 + ch[o10] * w10
                        + ch[o01] * w01 + ch[o11] * w11;
        op[(long long)c * PIX_PER_CROP] = acc;
    }
}

extern "C" void kernel_launch(void* const* d_in, const int* in_sizes, int n_in,
                              void* d_out, int out_size, void* d_ws, size_t ws_size,
                              hipStream_t stream) {
    const float* x     = (const float*)d_in[0];
    const float* boxes = (const float*)d_in[1];
    float* out         = (float*)d_out;

    const int nblocks = NB * NBOX * BLKS_PER_CROP;  // 512 * 60 = 30720
    rot_crop_kernel<<<nblocks, BLK, 0, stream>>>(x, boxes, out);
}

// Round 4
// 223.091 us; speedup vs baseline: 1.0125x; 1.0125x over previous
//
#include <hip/hip_runtime.h>
#include <math.h>

#define HOUT 48
#define WOUT 320
#define NB   8
#define NBOX 64
#define NC   3
#define IMH  1024
#define IMW  1024

#define PIX_PER_CROP (HOUT * WOUT)            // 15360
#define BLK 256
#define TILES_Y (HOUT / 16)                   // 3
#define TILES_X (WOUT / 16)                   // 20
#define BLKS_PER_CROP (TILES_Y * TILES_X)     // 60
#define NBLOCKS (NB * NBOX * BLKS_PER_CROP)   // 30720

__global__ __launch_bounds__(BLK) void rot_crop_kernel(
    const float* __restrict__ x,      // [NB, NC, IMH, IMW]
    const float* __restrict__ boxes,  // [NB, NBOX, 5]
    float* __restrict__ out)          // [NB*NBOX, NC, HOUT, WOUT]
{
    // XCD-aware bijective swizzle: dispatch d -> XCD d%8; give XCD k the
    // contiguous crop range of image k (NBLOCKS % 8 == 0 so this is bijective).
    const int bid = (blockIdx.x & 7) * (NBLOCKS / 8) + (blockIdx.x >> 3);

    const int bn = bid / BLKS_PER_CROP;            // crop index [0, 512)
    const int t  = bid % BLKS_PER_CROP;
    const int bi = t / TILES_X;                    // tile row [0, 3)
    const int bj = t % TILES_X;                    // tile col [0, 20)

    // Wave-tiled thread->pixel map: each wave owns a 4x16 output tile so its
    // 64 source taps form a compact rotated parallelogram (few cache lines),
    // and its 16-px row segments are 64B-line aligned for stores.
    const int lane = threadIdx.x & 63;
    const int wv   = threadIdx.x >> 6;             // 0..3
    const int i = bi * 16 + wv * 4 + (lane >> 4);  // output row
    const int j = bj * 16 + (lane & 15);           // output col
    const int b = bn / NBOX;                       // batch image

    // Box params — uniform per block (scalar loads).
    const float* box = boxes + bn * 5;
    const float cx  = box[0];
    const float cy  = box[1];
    const float bw  = box[2];
    const float bh  = box[3];
    const float ang = box[4];

    const float theta = ang * (-3.14159265358979323846f / 180.0f);
    float st, ct;
    __sincosf(theta, &st, &ct);
    const float bb = ct * 0.5f;
    const float aa = st * 0.5f;

    const float p0x = cx - aa * bh - bb * bw;
    const float p0y = cy + bb * bh - aa * bw;
    const float p1x = cx + aa * bh - bb * bw;
    const float p1y = cy - bb * bh - aa * bw;
    const float p2x = 2.0f * cx - p0x;
    const float p2y = 2.0f * cy - p0y;

    const float u = (float)j * (1.0f / (float)WOUT);
    const float v = (float)i * (1.0f / (float)HOUT);

    const float sx = p1x + u * (p2x - p1x) + v * (p0x - p1x);
    const float sy = p1y + u * (p2y - p1y) + v * (p0y - p1y);

    const float x0f = floorf(sx);
    const float y0f = floorf(sy);
    const float dx = sx - x0f;
    const float dy = sy - y0f;
    const int x0i = (int)x0f;
    const int y0i = (int)y0f;
    const int x1i = x0i + 1;
    const int y1i = y0i + 1;

    const bool vx0 = (x0i >= 0) & (x0i < IMW);
    const bool vx1 = (x1i >= 0) & (x1i < IMW);
    const bool vy0 = (y0i >= 0) & (y0i < IMH);
    const bool vy1 = (y1i >= 0) & (y1i < IMH);

    const int xc0 = min(max(x0i, 0), IMW - 1);
    const int xc1 = min(max(x1i, 0), IMW - 1);
    const int yc0 = min(max(y0i, 0), IMH - 1);
    const int yc1 = min(max(y1i, 0), IMH - 1);

    const float w00 = (1.0f - dx) * (1.0f - dy) * (float)(vx0 && vy0);
    const float w10 = dx * (1.0f - dy)          * (float)(vx1 && vy0);
    const float w01 = (1.0f - dx) * dy          * (float)(vx0 && vy1);
    const float w11 = dx * dy                   * (float)(vx1 && vy1);

    const int o00 = yc0 * IMW + xc0;
    const int o10 = yc0 * IMW + xc1;
    const int o01 = yc1 * IMW + xc0;
    const int o11 = yc1 * IMW + xc1;

    const float* img = x + (long long)b * NC * IMH * IMW;
    float* op = out + (long long)bn * NC * PIX_PER_CROP + i * WOUT + j;

#pragma unroll
    for (int c = 0; c < NC; ++c) {
        const float* ch = img + c * (IMH * IMW);
        const float acc = ch[o00] * w00 + ch[o10] * w10
                        + ch[o01] * w01 + ch[o11] * w11;
        op[c * PIX_PER_CROP] = acc;
    }
}

extern "C" void kernel_launch(void* const* d_in, const int* in_sizes, int n_in,
                              void* d_out, int out_size, void* d_ws, size_t ws_size,
                              hipStream_t stream) {
    const float* x     = (const float*)d_in[0];
    const float* boxes = (const float*)d_in[1];
    float* out         = (float*)d_out;

    rot_crop_kernel<<<NBLOCKS, BLK, 0, stream>>>(x, boxes, out);
}

// Round 6
// 194.540 us; speedup vs baseline: 1.1611x; 1.1468x over previous
//
#include <hip/hip_runtime.h>
#include <math.h>

#define HOUT 48
#define WOUT 320
#define NB   8
#define NBOX 64
#define NC   3
#define IMH  1024
#define IMW  1024

#define PIX_PER_CROP (HOUT * WOUT)            // 15360
#define BLK 256
#define TILES_Y (HOUT / 16)                   // 3
#define TILES_X (WOUT / 16)                   // 20
#define BLKS_PER_CROP (TILES_Y * TILES_X)     // 60
#define NBLOCKS (NB * NBOX * BLKS_PER_CROP)   // 30720

// 8-byte pair with only 4-byte alignment guarantee: dword-aligned
// global_load_dwordx2 is native/fast on CDNA.
struct __attribute__((packed, aligned(4))) F2 { float x, y; };

__global__ __launch_bounds__(BLK) void rot_crop_kernel(
    const float* __restrict__ x,      // [NB, NC, IMH, IMW]
    const float* __restrict__ boxes,  // [NB, NBOX, 5]
    float* __restrict__ out)          // [NB*NBOX, NC, HOUT, WOUT]
{
    // XCD-aware bijective swizzle (NBLOCKS % 8 == 0).
    const int bid = (blockIdx.x & 7) * (NBLOCKS / 8) + (blockIdx.x >> 3);

    const int bn = bid / BLKS_PER_CROP;            // crop index [0, 512)
    const int t  = bid % BLKS_PER_CROP;
    const int bi = t / TILES_X;                    // tile row [0, 3)
    const int bj = t % TILES_X;                    // tile col [0, 20)

    // 4x16 output tile per wave: compact rotated source footprint,
    // 64B-aligned 16-px store segments.
    const int lane = threadIdx.x & 63;
    const int wv   = threadIdx.x >> 6;             // 0..3
    const int i = bi * 16 + wv * 4 + (lane >> 4);  // output row
    const int j = bj * 16 + (lane & 15);           // output col
    const int b = bn / NBOX;                       // batch image

    // Box params — block-uniform -> scalar loads.
    const float* box = boxes + bn * 5;
    const float cx  = box[0];
    const float cy  = box[1];
    const float bw  = box[2];
    const float bh  = box[3];
    const float ang = box[4];

    const float theta = ang * (-3.14159265358979323846f / 180.0f);
    float st, ct;
    __sincosf(theta, &st, &ct);
    const float bb = ct * 0.5f;
    const float aa = st * 0.5f;

    const float p0x = cx - aa * bh - bb * bw;
    const float p0y = cy + bb * bh - aa * bw;
    const float p1x = cx + aa * bh - bb * bw;
    const float p1y = cy - bb * bh - aa * bw;
    const float p2x = 2.0f * cx - p0x;
    const float p2y = 2.0f * cy - p0y;

    const float u = (float)j * (1.0f / (float)WOUT);
    const float v = (float)i * (1.0f / (float)HOUT);

    const float sx = p1x + u * (p2x - p1x) + v * (p0x - p1x);
    const float sy = p1y + u * (p2y - p1y) + v * (p0y - p1y);

    const float x0f = floorf(sx);
    const float y0f = floorf(sy);
    const float dx = sx - x0f;
    const float dy = sy - y0f;
    const int x0i = (int)x0f;
    const int y0i = (int)y0f;
    const int y1i = y0i + 1;

    // Pair base column: always in [0, IMW-2], so the 8B pair never leaves its row.
    const int px = min(max(x0i, 0), IMW - 2);

    // Fold x-validity + clamping into pair weights. Matches reference exactly:
    //  x0 tap weight (1-dx) contributes iff x0i in [0,IMW) -> then x0i==px or px+1;
    //  x1 tap weight dx     contributes iff x1i in [0,IMW) -> then x1i==px or px+1.
    const float wx0 = 1.0f - dx;
    float b0 = 0.0f, b1 = 0.0f;
    if (x0i == px)      b0 += wx0;
    else if (x0i == px + 1) b1 += wx0;
    const int x1i = x0i + 1;
    if (x1i == px)      b0 += dx;
    else if (x1i == px + 1) b1 += dx;

    const bool vy0 = (y0i >= 0) & (y0i < IMH);
    const bool vy1 = (y1i >= 0) & (y1i < IMH);
    const int yc0 = min(max(y0i, 0), IMH - 1);
    const int yc1 = min(max(y1i, 0), IMH - 1);
    const float wy0 = (1.0f - dy) * (float)vy0;
    const float wy1 = dy * (float)vy1;

    const int o0 = yc0 * IMW + px;
    const int o1 = yc1 * IMW + px;

    const float* img = x + (long long)b * NC * IMH * IMW;
    float* op = out + (long long)bn * NC * PIX_PER_CROP + i * WOUT + j;

#pragma unroll
    for (int c = 0; c < NC; ++c) {
        const float* ch = img + c * (IMH * IMW);
        const F2 r0 = *reinterpret_cast<const F2*>(ch + o0);
        const F2 r1 = *reinterpret_cast<const F2*>(ch + o1);
        const float acc = wy0 * (r0.x * b0 + r0.y * b1)
                        + wy1 * (r1.x * b0 + r1.y * b1);
        op[c * PIX_PER_CROP] = acc;
    }
}

extern "C" void kernel_launch(void* const* d_in, const int* in_sizes, int n_in,
                              void* d_out, int out_size, void* d_ws, size_t ws_size,
                              hipStream_t stream) {
    const float* x     = (const float*)d_in[0];
    const float* boxes = (const float*)d_in[1];
    float* out         = (float*)d_out;

    rot_crop_kernel<<<NBLOCKS, BLK, 0, stream>>>(x, boxes, out);
}